// Round 1
// baseline (1324.602 us; speedup 1.0000x reference)
//
#include <hip/hip_runtime.h>

// CRF-RNN mean-field iteration, MI355X.
// seg: [4][21][4096] f32, W: [4][4096][4096] f32, weights: [21][21] f32.
// qVals_{t+1}[b,d,m] = seg[b,d,m] - sum_e weights[d,e] * (sum_n softmax_d(qVals_t)[b,e,n] * W[b,m,n]) / rowsum_W[b,m]
// Rowsum is fused into the matmul pass (same rows streamed anyway) -> 5 W passes total.

#define BSZ 4
#define DC 21      // classes
#define NN 4096    // pixels
#define NK 512     // n-chunk staged in LDS
#define RPW 4      // W-rows per wave
#define MBLK 16    // W-rows per block (4 waves * RPW)

__global__ __launch_bounds__(256) void softmax_k(const float* __restrict__ x,
                                                 float* __restrict__ q) {
    unsigned gid = blockIdx.x * 256u + threadIdx.x;   // 0 .. 16383
    unsigned b = gid >> 12;                            // / 4096
    unsigned n = gid & 4095u;
    const float* xb = x + (size_t)b * DC * NN + n;
    float v[DC];
    float m = -1e30f;
#pragma unroll
    for (int d = 0; d < DC; ++d) { v[d] = xb[(size_t)d * NN]; m = fmaxf(m, v[d]); }
    float s = 0.f;
#pragma unroll
    for (int d = 0; d < DC; ++d) { v[d] = __expf(v[d] - m); s += v[d]; }
    float inv = 1.f / s;
    float* qb = q + (size_t)b * DC * NN + n;
#pragma unroll
    for (int d = 0; d < DC; ++d) qb[(size_t)d * NN] = v[d] * inv;
}

__global__ __launch_bounds__(256) void crf_iter_k(const float* __restrict__ Q,
                                                  const float* __restrict__ W,
                                                  const float* __restrict__ wc,
                                                  const float* __restrict__ seg,
                                                  float* __restrict__ out) {
    __shared__ float qs[DC][NK];
    __shared__ float wcs[DC * DC];

    const unsigned tid  = threadIdx.x;
    const unsigned b    = blockIdx.x >> 8;        // 256 tiles per batch
    const unsigned tile = blockIdx.x & 255u;
    const unsigned wave = tid >> 6;
    const unsigned lane = tid & 63u;
    const unsigned m0   = tile * MBLK + wave * RPW;  // this wave's first W-row

    for (unsigned i = tid; i < DC * DC; i += 256u) wcs[i] = wc[i];

    const float* Wb = W + ((size_t)b * NN + m0) * NN;
    const float* Qb = Q + (size_t)b * DC * NN;

    float acc[RPW][DC];
#pragma unroll
    for (int r = 0; r < RPW; ++r)
#pragma unroll
        for (int d = 0; d < DC; ++d) acc[r][d] = 0.f;
    float accw[RPW] = {0.f, 0.f, 0.f, 0.f};

    for (int chunk = 0; chunk < NN / NK; ++chunk) {
        __syncthreads();   // previous compute done before overwriting qs
        // stage Q[b][:][chunk*NK .. +NK) into LDS, float4-coalesced
        for (unsigned i = tid; i < DC * (NK / 4); i += 256u) {
            unsigned d  = i / (NK / 4);
            unsigned c4 = i % (NK / 4);
            float4 qv = *(const float4*)(Qb + (size_t)d * NN + chunk * NK + c4 * 4);
            *(float4*)&qs[d][c4 * 4] = qv;
        }
        __syncthreads();
#pragma unroll
        for (int half = 0; half < NK / 256; ++half) {
            const unsigned nb = chunk * NK + half * 256 + lane * 4;  // global n
            const unsigned cl = half * 256 + lane * 4;               // lds col
            float4 w[RPW];
#pragma unroll
            for (int r = 0; r < RPW; ++r)
                w[r] = *(const float4*)(Wb + (size_t)r * NN + nb);
#pragma unroll
            for (int r = 0; r < RPW; ++r)
                accw[r] += (w[r].x + w[r].y) + (w[r].z + w[r].w);
#pragma unroll
            for (int d = 0; d < DC; ++d) {
                float4 qv = *(const float4*)&qs[d][cl];
#pragma unroll
                for (int r = 0; r < RPW; ++r)
                    acc[r][d] += qv.x * w[r].x + qv.y * w[r].y +
                                 qv.z * w[r].z + qv.w * w[r].w;
            }
        }
    }

    // butterfly allreduce across the 64 lanes (each lane summed a n-subset)
#pragma unroll
    for (int off = 32; off > 0; off >>= 1) {
#pragma unroll
        for (int r = 0; r < RPW; ++r) {
            accw[r] += __shfl_xor(accw[r], off, 64);
#pragma unroll
            for (int d = 0; d < DC; ++d)
                acc[r][d] += __shfl_xor(acc[r][d], off, 64);
        }
    }

    // epilogue: lane l (<21) produces class d=l for each of the wave's 4 rows
    if (lane < DC) {
#pragma unroll
        for (int r = 0; r < RPW; ++r) {
            float inv = 1.f / accw[r];
            float s = 0.f;
#pragma unroll
            for (int e = 0; e < DC; ++e) s += wcs[lane * DC + e] * acc[r][e];
            size_t oi = ((size_t)b * DC + lane) * NN + (m0 + r);
            out[oi] = seg[oi] - s * inv;
        }
    }
}

extern "C" void kernel_launch(void* const* d_in, const int* in_sizes, int n_in,
                              void* d_out, int out_size, void* d_ws, size_t ws_size,
                              hipStream_t stream) {
    const float* seg = (const float*)d_in[0];
    const float* W   = (const float*)d_in[1];
    const float* wc  = (const float*)d_in[2];
    float* out = (float*)d_out;
    float* Q   = (float*)d_ws;   // 4*21*4096 floats = 1.31 MiB

    const dim3 smx_grid(BSZ * NN / 256), smx_blk(256);
    const dim3 mm_grid(BSZ * (NN / MBLK)), mm_blk(256);

    // iter 0: qVals = seg
    softmax_k<<<smx_grid, smx_blk, 0, stream>>>(seg, Q);
    crf_iter_k<<<mm_grid, mm_blk, 0, stream>>>(Q, W, wc, seg, out);
    // iters 1..4
    for (int it = 1; it < 5; ++it) {
        softmax_k<<<smx_grid, smx_blk, 0, stream>>>(out, Q);
        crf_iter_k<<<mm_grid, mm_blk, 0, stream>>>(Q, W, wc, seg, out);
    }
}

// Round 2
// 1096.769 us; speedup vs baseline: 1.2077x; 1.2077x over previous
//
#include <hip/hip_runtime.h>
#include <math.h>

// CRF-RNN mean-field, MI355X.  seg:[4][21][4096] f32, W:[4][4096][4096] f32, wc:[21][21] f32.
// qVals_{t+1}[b,d,m] = seg[b,d,m] - (sum_e wc[d,e] * sum_n Q_t[b,e,n]*W[b,m,n]) / rowsum_W[b,m]
// Q_t = softmax_d(qVals_t).  Rowsum fused into the streaming pass.
//
// Structure: 1-wave blocks (64 thr), grid 2048 (= 4 batch x 512 row-tiles), no LDS, no barriers.
// Lane = (group g in [0,4), sub-lane l in [0,16)). Group g owns rows {tile*8+2g, +1} over full n.
// W loads: 16 lanes x float4 = 256 B contiguous per row segment (2 cache lines).
// Q loads: identical addrs across the 4 groups -> 256 B distinct per instr, L1/L2 broadcast.
// Reduction: 4-level __shfl_xor confined to 16-lane groups (offsets 1,2,4,8).
// Epilogue fuses compat-mix, /rowsum, seg-subtract, and next iter's softmax (Q ping-pong in ws).

#define DC 21
#define NN 4096
#define BS 4

__global__ __launch_bounds__(256) void softmax0_k(const float* __restrict__ x,
                                                  float* __restrict__ q) {
    unsigned gid = blockIdx.x * 256u + threadIdx.x;   // 0..16383
    unsigned b = gid >> 12;
    unsigned n = gid & 4095u;
    const float* xb = x + (size_t)b * DC * NN + n;
    float v[DC];
    float m = -1e30f;
#pragma unroll
    for (int d = 0; d < DC; ++d) { v[d] = xb[(size_t)d * NN]; m = fmaxf(m, v[d]); }
    float s = 0.f;
#pragma unroll
    for (int d = 0; d < DC; ++d) { v[d] = __expf(v[d] - m); s += v[d]; }
    float inv = 1.f / s;
    float* qb = q + (size_t)b * DC * NN + n;
#pragma unroll
    for (int d = 0; d < DC; ++d) qb[(size_t)d * NN] = v[d] * inv;
}

__global__ __launch_bounds__(64) void crf_iter_k(const float* __restrict__ Q,
                                                 const float* __restrict__ W,
                                                 const float* __restrict__ wc,
                                                 const float* __restrict__ seg,
                                                 float* __restrict__ qnext,
                                                 float* __restrict__ out,
                                                 int write_q, int write_out) {
    const int lane = threadIdx.x;
    const int g = lane >> 4;          // group 0..3
    const int l = lane & 15;          // sub-lane 0..15
    const int b  = blockIdx.x >> 9;   // batch
    const int rb = blockIdx.x & 511;  // row tile
    const int m0 = rb * 8 + g * 2;    // this group's rows: m0, m0+1

    const float4* Wr0 = (const float4*)(W + ((size_t)b * NN + m0) * NN + l * 4);
    const float4* Wr1 = (const float4*)(W + ((size_t)b * NN + m0 + 1) * NN + l * 4);
    const float4* Qf4 = (const float4*)(Q + (size_t)b * DC * NN + l * 4);

    float acc0[DC], acc1[DC];
#pragma unroll
    for (int d = 0; d < DC; ++d) { acc0[d] = 0.f; acc1[d] = 0.f; }
    float rs0 = 0.f, rs1 = 0.f;

    // k-loop over n: 64 steps x 64 n per step (16 lanes x float4)
#pragma unroll 2
    for (int s = 0; s < 64; ++s) {
        float4 wa = Wr0[s * 16];
        float4 wb = Wr1[s * 16];
        rs0 += (wa.x + wa.y) + (wa.z + wa.w);
        rs1 += (wb.x + wb.y) + (wb.z + wb.w);
#pragma unroll
        for (int d = 0; d < DC; ++d) {
            float4 qv = Qf4[d * 1024 + s * 16];
            acc0[d] += qv.x * wa.x + qv.y * wa.y + qv.z * wa.z + qv.w * wa.w;
            acc1[d] += qv.x * wb.x + qv.y * wb.y + qv.z * wb.z + qv.w * wb.w;
        }
    }

    // 16-lane group allreduce (offsets stay inside the 16-lane group)
#pragma unroll
    for (int off = 1; off < 16; off <<= 1) {
        rs0 += __shfl_xor(rs0, off);
        rs1 += __shfl_xor(rs1, off);
#pragma unroll
        for (int d = 0; d < DC; ++d) {
            acc0[d] += __shfl_xor(acc0[d], off);
            acc1[d] += __shfl_xor(acc1[d], off);
        }
    }

    const float inv0 = 1.f / rs0;
    const float inv1 = 1.f / rs1;

    // lane l produces classes d1=l and d2=l+16 (d2 only for l<5)
    const int d1 = l;
    const int d2 = l + 16;
    const bool has2 = (d2 < DC);

    float u0a = 0.f, u1a = 0.f, u0b = 0.f, u1b = 0.f;
#pragma unroll
    for (int e = 0; e < DC; ++e) {
        float w1 = wc[d1 * DC + e];
        u0a += w1 * acc0[e];
        u1a += w1 * acc1[e];
    }
    if (has2) {
#pragma unroll
        for (int e = 0; e < DC; ++e) {
            float w2 = wc[d2 * DC + e];
            u0b += w2 * acc0[e];
            u1b += w2 * acc1[e];
        }
    }

    const size_t base = (size_t)b * DC * NN;
    const size_t i0a = base + (size_t)d1 * NN + m0;
    const size_t i0b = base + (size_t)d2 * NN + m0;

    float v0a = seg[i0a]     - u0a * inv0;   // row m0,   class d1
    float v1a = seg[i0a + 1] - u1a * inv1;   // row m0+1, class d1
    float v0b = 0.f, v1b = 0.f;
    if (has2) {
        v0b = seg[i0b]     - u0b * inv0;
        v1b = seg[i0b + 1] - u1b * inv1;
    }

    if (write_out) {
        out[i0a]     = v0a;
        out[i0a + 1] = v1a;
        if (has2) { out[i0b] = v0b; out[i0b + 1] = v1b; }
    }

    if (write_q) {
        // softmax over the 21 classes of each row (values spread over the 16-lane group)
        float mx0 = has2 ? fmaxf(v0a, v0b) : v0a;
        float mx1 = has2 ? fmaxf(v1a, v1b) : v1a;
#pragma unroll
        for (int off = 1; off < 16; off <<= 1) {
            mx0 = fmaxf(mx0, __shfl_xor(mx0, off));
            mx1 = fmaxf(mx1, __shfl_xor(mx1, off));
        }
        float e0a = __expf(v0a - mx0);
        float e1a = __expf(v1a - mx1);
        float e0b = has2 ? __expf(v0b - mx0) : 0.f;
        float e1b = has2 ? __expf(v1b - mx1) : 0.f;
        float s0 = e0a + e0b;
        float s1 = e1a + e1b;
#pragma unroll
        for (int off = 1; off < 16; off <<= 1) {
            s0 += __shfl_xor(s0, off);
            s1 += __shfl_xor(s1, off);
        }
        float is0 = 1.f / s0;
        float is1 = 1.f / s1;
        qnext[i0a]     = e0a * is0;
        qnext[i0a + 1] = e1a * is1;
        if (has2) {
            qnext[i0b]     = e0b * is0;
            qnext[i0b + 1] = e1b * is1;
        }
    }
}

extern "C" void kernel_launch(void* const* d_in, const int* in_sizes, int n_in,
                              void* d_out, int out_size, void* d_ws, size_t ws_size,
                              hipStream_t stream) {
    const float* seg = (const float*)d_in[0];
    const float* W   = (const float*)d_in[1];
    const float* wc  = (const float*)d_in[2];
    float* out = (float*)d_out;

    float* Qa = (float*)d_ws;                       // 4*21*4096 f32 = 1.31 MiB
    float* Qb = Qa + (size_t)BS * DC * NN;          // ping-pong (ws >= 2.63 MiB)

    softmax0_k<<<dim3(BS * NN / 256), dim3(256), 0, stream>>>(seg, Qa);

    const float* qin = Qa;
    float* qout = Qb;
    for (int it = 0; it < 5; ++it) {
        crf_iter_k<<<dim3(2048), dim3(64), 0, stream>>>(
            qin, W, wc, seg, qout, out, (it < 4) ? 1 : 0, (it == 4) ? 1 : 0);
        const float* t = qin; qin = qout; qout = (float*)t;
    }
}